// Round 1
// baseline (2888.739 us; speedup 1.0000x reference)
//
#include <hip/hip_runtime.h>
#include <math.h>

#define HEADS 8
#define POINTS 4
#define BSZ 2
#define CDIM 256
#define HH 200
#define WW 200
#define LQ (HH * WW)      // 40000
#define NLAYERS 3

// ---------------------------------------------------------------------------
// Sine positional encoding: pos[l, c], l in [0,LQ), c in [0,256)
// c < 128: features of y = (l/W)+1 ; c >= 128: features of x = (l%W)+1
// channel cc (mod 128): even -> sin(coord/t), odd -> cos(coord/t),
// t = 10000^(2*floor(cc/2)/128)
// ---------------------------------------------------------------------------
__global__ __launch_bounds__(256)
void pos_kernel(float* __restrict__ pos)
{
    const int idx = blockIdx.x * 256 + threadIdx.x;   // grid sized exactly
    const int c = idx & 255;
    const int l = idx >> 8;
    const int cc = c & 127;
    const float coord = (c < 128) ? (float)(l / WW + 1) : (float)(l % WW + 1);
    const float expo = (float)(2 * (cc >> 1)) * (1.0f / 128.0f);
    const float t = powf(10000.0f, expo);
    const float ph = coord / t;
    pos[idx] = (cc & 1) ? cosf(ph) : sinf(ph);
}

// ---------------------------------------------------------------------------
// Tiled GEMM: C[m,n] = sum_k Aeff[m,k]*B[n,k] + bias[n]   (B is [N,K] row-major)
// Aeff = (AT ? A^T : A) (+ Aadd if non-null; only valid when !AT, lda==K)
// Tile 64x64, BK=16, 256 threads, 4x4 per-thread microtile.
// M must be a multiple of 64; K a multiple of 16; N a multiple of 4.
// ---------------------------------------------------------------------------
#define TS 64
#define BKK 16
#define LPAD 68

template<bool AT, bool RELU>
__global__ __launch_bounds__(256)
void gemm_kernel(const float* __restrict__ A, size_t aBatch, int lda,
                 const float* __restrict__ Aadd,
                 const float* __restrict__ B,
                 const float* __restrict__ bias,
                 float* __restrict__ Cout, size_t cBatch,
                 int M, int N, int K)
{
    __shared__ float As[BKK][LPAD];
    __shared__ float Bs[BKK][LPAD];
    const int tid = threadIdx.x;
    const int tn = tid & 15;
    const int tm = tid >> 4;
    const int rowBase = blockIdx.y * TS;
    const int colBase = blockIdx.x * TS;
    const int b = blockIdx.z;
    const float* Ab = A + (size_t)b * aBatch;
    float* Cb = Cout + (size_t)b * cBatch;

    float acc[4][4];
    #pragma unroll
    for (int i = 0; i < 4; i++)
        #pragma unroll
        for (int j = 0; j < 4; j++) acc[i][j] = 0.f;

    for (int k0 = 0; k0 < K; k0 += BKK) {
        // ---- stage A tile: As[k][m] ----
        if (AT) {
            const int k = tid >> 4;            // 0..15
            const int m4 = (tid & 15) * 4;     // 0..60
            const float4 av = *(const float4*)(Ab + (size_t)(k0 + k) * lda + rowBase + m4);
            *(float4*)&As[k][m4] = av;
        } else {
            const int m = tid >> 2;            // 0..63
            const int kq = (tid & 3) * 4;      // 0,4,8,12
            float4 av = *(const float4*)(Ab + (size_t)(rowBase + m) * lda + k0 + kq);
            if (Aadd) {
                const float4 pv = *(const float4*)(Aadd + (size_t)(rowBase + m) * K + k0 + kq);
                av.x += pv.x; av.y += pv.y; av.z += pv.z; av.w += pv.w;
            }
            As[kq + 0][m] = av.x; As[kq + 1][m] = av.y;
            As[kq + 2][m] = av.z; As[kq + 3][m] = av.w;
        }
        // ---- stage B tile: Bs[k][n] ----
        {
            const int n = tid >> 2;            // 0..63
            const int kq = (tid & 3) * 4;
            float4 bv = make_float4(0.f, 0.f, 0.f, 0.f);
            if (colBase + n < N)
                bv = *(const float4*)(B + (size_t)(colBase + n) * K + k0 + kq);
            Bs[kq + 0][n] = bv.x; Bs[kq + 1][n] = bv.y;
            Bs[kq + 2][n] = bv.z; Bs[kq + 3][n] = bv.w;
        }
        __syncthreads();
        #pragma unroll
        for (int kk = 0; kk < BKK; kk++) {
            const float4 a4 = *(const float4*)&As[kk][tm * 4];
            const float4 b4 = *(const float4*)&Bs[kk][tn * 4];
            const float a[4] = {a4.x, a4.y, a4.z, a4.w};
            const float bb[4] = {b4.x, b4.y, b4.z, b4.w};
            #pragma unroll
            for (int i = 0; i < 4; i++)
                #pragma unroll
                for (int j = 0; j < 4; j++)
                    acc[i][j] = fmaf(a[i], bb[j], acc[i][j]);
        }
        __syncthreads();
    }

    const int cb = colBase + tn * 4;
    if (cb < N) {
        const float4 bz = *(const float4*)(bias + cb);
        #pragma unroll
        for (int i = 0; i < 4; i++) {
            const int r = rowBase + tm * 4 + i;
            float4 v;
            v.x = acc[i][0] + bz.x; v.y = acc[i][1] + bz.y;
            v.z = acc[i][2] + bz.z; v.w = acc[i][3] + bz.w;
            if (RELU) {
                v.x = fmaxf(v.x, 0.f); v.y = fmaxf(v.y, 0.f);
                v.z = fmaxf(v.z, 0.f); v.w = fmaxf(v.w, 0.f);
            }
            *(float4*)(Cb + (size_t)r * N + cb) = v;
        }
    }
}

// ---------------------------------------------------------------------------
// Deformable sampling: one block per (query, batch). 256 threads = 8 heads x 32d.
// x = w + off_x, y = h + off_y (align_corners=False algebra collapses).
// Zero padding outside [0,W)x[0,H). Softmax over the 4 points per head.
// ---------------------------------------------------------------------------
__global__ __launch_bounds__(256)
void sample_kernel(const float* __restrict__ val,   // [BS, LQ, 256]
                   const float* __restrict__ off,   // [BS, LQ, 64]
                   const float* __restrict__ awl,   // [BS, LQ, 32]
                   float* __restrict__ attn)        // [BS, LQ, 256]
{
    const int l = blockIdx.x;
    const int b = blockIdx.y;
    const int tid = threadIdx.x;
    __shared__ float sx[HEADS * POINTS];
    __shared__ float sy[HEADS * POINTS];
    __shared__ float sw[HEADS * POINTS];
    __shared__ float slog[HEADS * POINTS];

    if (tid < 32) {
        slog[tid] = awl[((size_t)b * LQ + l) * 32 + tid];
        const int hh = tid >> 2, p = tid & 3;
        const float ox = off[((size_t)b * LQ + l) * 64 + hh * 8 + p * 2 + 0];
        const float oy = off[((size_t)b * LQ + l) * 64 + hh * 8 + p * 2 + 1];
        sx[tid] = (float)(l % WW) + ox;
        sy[tid] = (float)(l / WW) + oy;
    }
    __syncthreads();
    if (tid < 32) {
        const int hh = tid >> 2;
        const float l0 = slog[hh * 4 + 0], l1 = slog[hh * 4 + 1];
        const float l2 = slog[hh * 4 + 2], l3 = slog[hh * 4 + 3];
        const float mx = fmaxf(fmaxf(l0, l1), fmaxf(l2, l3));
        const float e0 = expf(l0 - mx), e1 = expf(l1 - mx);
        const float e2 = expf(l2 - mx), e3 = expf(l3 - mx);
        const float inv = 1.0f / (e0 + e1 + e2 + e3);
        const float ee[4] = {e0, e1, e2, e3};
        sw[tid] = ee[tid & 3] * inv;
    }
    __syncthreads();

    const int c = tid;
    const int hh = c >> 5;
    const float* vb = val + (size_t)b * LQ * CDIM;
    float acc = 0.f;
    #pragma unroll
    for (int p = 0; p < POINTS; p++) {
        const float x = sx[hh * 4 + p];
        const float y = sy[hh * 4 + p];
        const float wt = sw[hh * 4 + p];
        const float x0f = floorf(x), y0f = floorf(y);
        const int x0 = (int)x0f, y0 = (int)y0f;
        const float wx = x - x0f, wy = y - y0f;
        float v00 = 0.f, v10 = 0.f, v01 = 0.f, v11 = 0.f;
        const bool xi0 = (x0 >= 0) && (x0 < WW);
        const bool xi1 = (x0 + 1 >= 0) && (x0 + 1 < WW);
        const bool yi0 = (y0 >= 0) && (y0 < HH);
        const bool yi1 = (y0 + 1 >= 0) && (y0 + 1 < HH);
        if (yi0) {
            const float* r = vb + (size_t)(y0 * WW) * CDIM;
            if (xi0) v00 = r[(size_t)x0 * CDIM + c];
            if (xi1) v10 = r[(size_t)(x0 + 1) * CDIM + c];
        }
        if (yi1) {
            const float* r = vb + (size_t)((y0 + 1) * WW) * CDIM;
            if (xi0) v01 = r[(size_t)x0 * CDIM + c];
            if (xi1) v11 = r[(size_t)(x0 + 1) * CDIM + c];
        }
        const float bil = v00 * (1.f - wx) * (1.f - wy) + v10 * wx * (1.f - wy)
                        + v01 * (1.f - wx) * wy + v11 * wx * wy;
        acc = fmaf(wt, bil, acc);
    }
    attn[((size_t)b * LQ + l) * CDIM + c] = acc;
}

// ---------------------------------------------------------------------------
// Fused residual + LayerNorm over 256-wide rows. One wave per row (64 lanes x
// float4), 4 rows per 256-thread block. In-place on io.
// ---------------------------------------------------------------------------
__global__ __launch_bounds__(256)
void ln_kernel(float* __restrict__ io,              // resid in, normalized out
               const float* __restrict__ add,
               const float* __restrict__ g,
               const float* __restrict__ beta)
{
    const int row = blockIdx.x * 4 + (threadIdx.x >> 6);
    const int lane = threadIdx.x & 63;
    float4* rp = (float4*)(io + (size_t)row * CDIM);
    const float4* ap = (const float4*)(add + (size_t)row * CDIM);
    float4 x = rp[lane];
    const float4 a = ap[lane];
    x.x += a.x; x.y += a.y; x.z += a.z; x.w += a.w;
    float s = x.x + x.y + x.z + x.w;
    float sq = x.x * x.x + x.y * x.y + x.z * x.z + x.w * x.w;
    #pragma unroll
    for (int o = 32; o >= 1; o >>= 1) {
        s += __shfl_xor(s, o, 64);
        sq += __shfl_xor(sq, o, 64);
    }
    const float mean = s * (1.0f / CDIM);
    const float var = sq * (1.0f / CDIM) - mean * mean;
    const float rstd = rsqrtf(var + 1e-5f);
    const float4 gv = *(const float4*)(g + lane * 4);
    const float4 bv = *(const float4*)(beta + lane * 4);
    float4 o4;
    o4.x = (x.x - mean) * rstd * gv.x + bv.x;
    o4.y = (x.y - mean) * rstd * gv.y + bv.y;
    o4.z = (x.z - mean) * rstd * gv.z + bv.z;
    o4.w = (x.w - mean) * rstd * gv.w + bv.w;
    rp[lane] = o4;
}

// ---------------------------------------------------------------------------
// Final transpose: out[b, l, c] -> d_out[b, c, l]. 32x32 LDS tiles; exact fit
// (LQ = 32*1250, C = 32*8).
// ---------------------------------------------------------------------------
__global__ __launch_bounds__(256)
void transpose_out(const float* __restrict__ in, float* __restrict__ outp)
{
    __shared__ float tile[32][33];
    const int b = blockIdx.z;
    const int l0 = blockIdx.x * 32;
    const int c0 = blockIdx.y * 32;
    const float* ib = in + (size_t)b * LQ * CDIM;
    float* ob = outp + (size_t)b * CDIM * LQ;
    #pragma unroll
    for (int j = 0; j < 32; j += 8) {
        const int l = l0 + threadIdx.y + j;
        const int c = c0 + threadIdx.x;
        tile[threadIdx.y + j][threadIdx.x] = ib[(size_t)l * CDIM + c];
    }
    __syncthreads();
    #pragma unroll
    for (int j = 0; j < 32; j += 8) {
        const int c = c0 + threadIdx.y + j;
        const int l = l0 + threadIdx.x;
        ob[(size_t)c * LQ + l] = tile[threadIdx.x][threadIdx.y + j];
    }
}

// ---------------------------------------------------------------------------
extern "C" void kernel_launch(void* const* d_in, const int* in_sizes, int n_in,
                              void* d_out, int out_size, void* d_ws, size_t ws_size,
                              hipStream_t stream)
{
    const float* bev      = (const float*)d_in[0];
    const float* proj_q_w = (const float*)d_in[1];
    const float* proj_q_b = (const float*)d_in[2];
    const float* off_w    = (const float*)d_in[3];
    const float* off_b    = (const float*)d_in[4];
    const float* aw_w     = (const float*)d_in[5];
    const float* aw_b     = (const float*)d_in[6];
    const float* vp_w     = (const float*)d_in[7];
    const float* vp_b     = (const float*)d_in[8];
    const float* op_w     = (const float*)d_in[9];
    const float* op_b     = (const float*)d_in[10];
    const float* ln1_g    = (const float*)d_in[11];
    const float* ln1_b    = (const float*)d_in[12];
    const float* l1_w     = (const float*)d_in[13];
    const float* l1_b     = (const float*)d_in[14];
    const float* l2_w     = (const float*)d_in[15];
    const float* l2_b     = (const float*)d_in[16];
    const float* ln2_g    = (const float*)d_in[17];
    const float* ln2_b    = (const float*)d_in[18];
    float* outp = (float*)d_out;

    float* w = (float*)d_ws;
    const size_t P = (size_t)BSZ * LQ * CDIM;          // 20,480,000 floats
    float* buf_out  = w;                               // [BS, LQ, C]
    float* buf_val  = w + P;                           // [BS, LQ, C] (also tmp)
    float* buf_attn = w + 2 * P;                       // [BS, LQ, C]
    float* buf_pos  = w + 3 * P;                       // [LQ, C]
    float* buf_off  = buf_pos + (size_t)LQ * CDIM;     // [BS, LQ, 64]
    float* buf_aw   = buf_off + (size_t)BSZ * LQ * 64; // [BS, LQ, 32]

    const dim3 blk(256);
    const dim3 gemm_grid_full(CDIM / TS, LQ / TS, BSZ);   // N=256
    const dim3 gemm_grid_1(1, LQ / TS, BSZ);              // N<=64
    const size_t rowStride = (size_t)LQ * CDIM;

    // positional encoding (layer-invariant)
    pos_kernel<<<dim3((LQ * CDIM) / 256), blk, 0, stream>>>(buf_pos);

    // input projection: out = bev^T @ proj_q_w^T + b   (A read transposed)
    gemm_kernel<true, false><<<gemm_grid_full, blk, 0, stream>>>(
        bev, (size_t)CDIM * LQ, LQ, nullptr, proj_q_w, proj_q_b,
        buf_out, rowStride, LQ, CDIM, CDIM);

    for (int i = 0; i < NLAYERS; i++) {
        const float* vpw = vp_w + (size_t)i * CDIM * CDIM;
        const float* vpb = vp_b + (size_t)i * CDIM;
        const float* ofw = off_w + (size_t)i * 64 * CDIM;
        const float* ofb = off_b + (size_t)i * 64;
        const float* awwp = aw_w + (size_t)i * 32 * CDIM;
        const float* awbp = aw_b + (size_t)i * 32;
        const float* opw = op_w + (size_t)i * CDIM * CDIM;
        const float* opb = op_b + (size_t)i * CDIM;
        const float* l1wp = l1_w + (size_t)i * CDIM * CDIM;
        const float* l1bp = l1_b + (size_t)i * CDIM;
        const float* l2wp = l2_w + (size_t)i * CDIM * CDIM;
        const float* l2bp = l2_b + (size_t)i * CDIM;

        // value = out @ vp_w^T + vp_b
        gemm_kernel<false, false><<<gemm_grid_full, blk, 0, stream>>>(
            buf_out, rowStride, CDIM, nullptr, vpw, vpb,
            buf_val, rowStride, LQ, CDIM, CDIM);
        // off = (out + pos) @ off_w^T + off_b   [N=64]
        gemm_kernel<false, false><<<gemm_grid_1, blk, 0, stream>>>(
            buf_out, rowStride, CDIM, buf_pos, ofw, ofb,
            buf_off, (size_t)LQ * 64, LQ, 64, CDIM);
        // aw_logits = (out + pos) @ aw_w^T + aw_b   [N=32]
        gemm_kernel<false, false><<<gemm_grid_1, blk, 0, stream>>>(
            buf_out, rowStride, CDIM, buf_pos, awwp, awbp,
            buf_aw, (size_t)LQ * 32, LQ, 32, CDIM);
        // deformable sampling -> attn
        sample_kernel<<<dim3(LQ, BSZ), blk, 0, stream>>>(
            buf_val, buf_off, buf_aw, buf_attn);
        // attn_out = attn @ op_w^T + op_b  (into buf_val; value is dead now)
        gemm_kernel<false, false><<<gemm_grid_full, blk, 0, stream>>>(
            buf_attn, rowStride, CDIM, nullptr, opw, opb,
            buf_val, rowStride, LQ, CDIM, CDIM);
        // out = LN(out + attn_out)
        ln_kernel<<<dim3(BSZ * LQ / 4), blk, 0, stream>>>(buf_out, buf_val, ln1_g + (size_t)i * CDIM, ln1_b + (size_t)i * CDIM);
        // hidden = relu(out @ l1_w^T + l1_b)
        gemm_kernel<false, true><<<gemm_grid_full, blk, 0, stream>>>(
            buf_out, rowStride, CDIM, nullptr, l1wp, l1bp,
            buf_val, rowStride, LQ, CDIM, CDIM);
        // ffn = hidden @ l2_w^T + l2_b
        gemm_kernel<false, false><<<gemm_grid_full, blk, 0, stream>>>(
            buf_val, rowStride, CDIM, nullptr, l2wp, l2bp,
            buf_attn, rowStride, LQ, CDIM, CDIM);
        // out = LN(out + ffn)
        ln_kernel<<<dim3(BSZ * LQ / 4), blk, 0, stream>>>(buf_out, buf_attn, ln2_g + (size_t)i * CDIM, ln2_b + (size_t)i * CDIM);
    }

    // [b, l, c] -> [b, c, l]
    transpose_out<<<dim3(LQ / 32, CDIM / 32, BSZ), dim3(32, 8), 0, stream>>>(buf_out, outp);
}

// Round 2
// 1694.947 us; speedup vs baseline: 1.7043x; 1.7043x over previous
//
#include <hip/hip_runtime.h>
#include <math.h>

#define HEADS 8
#define POINTS 4
#define BSZ 2
#define CDIM 256
#define HH 200
#define WW 200
#define LQ (HH * WW)          // 40000
#define MTOT (BSZ * LQ)       // 80000 rows, batch folded into M
#define NLAYERS 3

typedef __attribute__((ext_vector_type(8))) short shortx8;   // 8 bf16 = 4 VGPR
typedef __attribute__((ext_vector_type(4))) float floatx4;

__device__ __forceinline__ ushort f2b(float f) {
    union { float f; unsigned u; } v; v.f = f;
    unsigned r = v.u + 0x7fffu + ((v.u >> 16) & 1u);   // RNE
    return (ushort)(r >> 16);
}
__device__ __forceinline__ float b2f(ushort b) {
    union { unsigned u; float f; } v; v.u = ((unsigned)b) << 16;
    return v.f;
}

// ---------------------------------------------------------------------------
// fp32 -> bf16 convert (n multiple of 1024)
// ---------------------------------------------------------------------------
__global__ __launch_bounds__(256)
void cvt_kernel(const float* __restrict__ in, ushort* __restrict__ out)
{
    const int i = (blockIdx.x * 256 + threadIdx.x) * 4;
    const float4 v = *(const float4*)(in + i);
    ushort4 o;
    o.x = f2b(v.x); o.y = f2b(v.y); o.z = f2b(v.z); o.w = f2b(v.w);
    *(ushort4*)(out + i) = o;
}

// ---------------------------------------------------------------------------
// Build packed off+aw weight [3][128][256] bf16 (rows 0..63 off, 64..95 aw,
// 96..127 zero) and bias [3][128] fp32.
// ---------------------------------------------------------------------------
__global__ __launch_bounds__(256)
void build_offaw(const float* __restrict__ offw, const float* __restrict__ offb,
                 const float* __restrict__ aww, const float* __restrict__ awb,
                 ushort* __restrict__ wout, float* __restrict__ bout)
{
    const int blk = blockIdx.x;          // 3*128 blocks
    const int i = blk >> 7;
    const int r = blk & 127;
    const int c = threadIdx.x;
    float v = 0.f;
    if (r < 64)      v = offw[((size_t)i * 64 + r) * CDIM + c];
    else if (r < 96) v = aww[((size_t)i * 32 + (r - 64)) * CDIM + c];
    wout[((size_t)i * 128 + r) * CDIM + c] = f2b(v);
    if (c == 0) {
        float bb = 0.f;
        if (r < 64)      bb = offb[i * 64 + r];
        else if (r < 96) bb = awb[i * 32 + (r - 64)];
        bout[i * 128 + r] = bb;
    }
}

// ---------------------------------------------------------------------------
// Sine positional encoding -> bf16 [LQ, 256]
// ---------------------------------------------------------------------------
__global__ __launch_bounds__(256)
void pos_kernel(ushort* __restrict__ pos)
{
    const int idx = blockIdx.x * 256 + threadIdx.x;
    const int c = idx & 255;
    const int l = idx >> 8;
    const int cc = c & 127;
    const float coord = (c < 128) ? (float)(l / WW + 1) : (float)(l % WW + 1);
    const float expo = (float)(2 * (cc >> 1)) * (1.0f / 128.0f);
    const float t = powf(10000.0f, expo);
    const float ph = coord / t;
    pos[idx] = f2b((cc & 1) ? cosf(ph) : sinf(ph));
}

// ---------------------------------------------------------------------------
// bev [BS, C, HW] fp32 -> [BS*HW, C] bf16 (32x32 LDS transpose tiles)
// ---------------------------------------------------------------------------
__global__ __launch_bounds__(256)
void bevT_kernel(const float* __restrict__ in, ushort* __restrict__ out)
{
    __shared__ float tile[32][33];
    const int b = blockIdx.z;
    const int l0 = blockIdx.x * 32;
    const int c0 = blockIdx.y * 32;
    const float* ib = in + (size_t)b * CDIM * LQ;
    ushort* ob = out + (size_t)b * LQ * CDIM;
    #pragma unroll
    for (int j = 0; j < 32; j += 8)
        tile[threadIdx.y + j][threadIdx.x] =
            ib[(size_t)(c0 + threadIdx.y + j) * LQ + l0 + threadIdx.x];
    __syncthreads();
    #pragma unroll
    for (int j = 0; j < 32; j += 8)
        ob[(size_t)(l0 + threadIdx.y + j) * CDIM + c0 + threadIdx.x] =
            f2b(tile[threadIdx.x][threadIdx.y + j]);
}

// ---------------------------------------------------------------------------
// MFMA bf16 GEMM: C[m,n] = sum_k A[m,k]*B[n,k] + bias[n]
// A [M,K] bf16, B [N,K] bf16, fp32 accumulate. 128x128 tile, BK=32,
// 256 thr = 4 waves (2x2 of 64x64), 16x16x32 MFMA, 4x4 tiles/wave.
// M mult of 128 (grid.y), N mult of 128 (grid.x), K mult of 32.
// Epilogue: optional RELU, fp32 store, bf16 store, q=bf16(out+pos) store.
// ---------------------------------------------------------------------------
#define LSTR 40   // LDS row stride in shorts (80 B = 5*16, breaks 2^k banks)

template<bool RELU, bool F32OUT, bool BF16OUT, bool QOUT>
__global__ __launch_bounds__(256)
void mfma_gemm(const ushort* __restrict__ A, const ushort* __restrict__ B,
               const float* __restrict__ bias,
               float* __restrict__ Cf, ushort* __restrict__ Cb,
               ushort* __restrict__ Cq, const ushort* __restrict__ posb,
               int N, int K)
{
    __shared__ ushort As[128 * LSTR];
    __shared__ ushort Bs[128 * LSTR];
    const int tid = threadIdx.x;
    const int lane = tid & 63;
    const int wave = tid >> 6;
    const int wr = (wave >> 1) * 64;
    const int wc = (wave & 1) * 64;
    const int rowBase = blockIdx.y * 128;
    const int colBase = blockIdx.x * 128;

    floatx4 acc[4][4];
    #pragma unroll
    for (int i = 0; i < 4; i++)
        #pragma unroll
        for (int j = 0; j < 4; j++) {
            floatx4 z = {0.f, 0.f, 0.f, 0.f};
            acc[i][j] = z;
        }

    const int strow = tid >> 2;          // 0..63
    const int stcol = (tid & 3) * 8;     // 0,8,16,24
    const int kq = (lane >> 4) * 8;      // fragment k offset
    const int lr = lane & 15;

    for (int k0 = 0; k0 < K; k0 += 32) {
        #pragma unroll
        for (int j = 0; j < 2; j++) {
            const int r = j * 64 + strow;
            const uint4 av = *(const uint4*)(A + (size_t)(rowBase + r) * K + k0 + stcol);
            const uint4 bv = *(const uint4*)(B + (size_t)(colBase + r) * K + k0 + stcol);
            *(uint4*)(As + r * LSTR + stcol) = av;
            *(uint4*)(Bs + r * LSTR + stcol) = bv;
        }
        __syncthreads();
        shortx8 af[4], bf[4];
        #pragma unroll
        for (int t = 0; t < 4; t++) {
            af[t] = *(const shortx8*)(As + (wr + t * 16 + lr) * LSTR + kq);
            bf[t] = *(const shortx8*)(Bs + (wc + t * 16 + lr) * LSTR + kq);
        }
        #pragma unroll
        for (int mt = 0; mt < 4; mt++)
            #pragma unroll
            for (int nt = 0; nt < 4; nt++)
                acc[mt][nt] = __builtin_amdgcn_mfma_f32_16x16x32_bf16(
                    af[mt], bf[nt], acc[mt][nt], 0, 0, 0);
        __syncthreads();
    }

    // epilogue: C/D layout col=lane&15, row=(lane>>4)*4+reg  [m89/m91 verified]
    const int colB = colBase + wc + lr;
    const int rowB = rowBase + wr + (lane >> 4) * 4;
    #pragma unroll
    for (int mt = 0; mt < 4; mt++) {
        #pragma unroll
        for (int r = 0; r < 4; r++) {
            const int m = rowB + mt * 16 + r;
            const int pr = (m >= LQ) ? m - LQ : m;   // pos row (batch-folded)
            #pragma unroll
            for (int nt = 0; nt < 4; nt++) {
                const int n = colB + nt * 16;
                float v = acc[mt][nt][r] + bias[n];
                if (RELU) v = fmaxf(v, 0.f);
                if (F32OUT) Cf[(size_t)m * N + n] = v;
                if (BF16OUT) Cb[(size_t)m * N + n] = f2b(v);
                if (QOUT) {
                    const float pv = b2f(posb[(size_t)pr * CDIM + n]);
                    Cq[(size_t)m * N + n] = f2b(v + pv);
                }
            }
        }
    }
}

// ---------------------------------------------------------------------------
// Deformable sampling: block per (query l, batch b). 256 thr = 8 heads x 32 ch.
// val bf16 [MTOT,256]; offaw fp32 [MTOT,128] (cols 0..63 offsets, 64..95 aw
// logits); out attn bf16 [MTOT,256].
// ---------------------------------------------------------------------------
__global__ __launch_bounds__(256)
void sample_kernel(const ushort* __restrict__ val,
                   const float* __restrict__ offaw,
                   ushort* __restrict__ attn)
{
    const int l = blockIdx.x;
    const int b = blockIdx.y;
    const size_t m = (size_t)b * LQ + l;
    const int tid = threadIdx.x;
    __shared__ float sx[32], sy[32], sw[32], slog[32];

    if (tid < 32) {
        const float* row = offaw + m * 128;
        slog[tid] = row[64 + tid];
        sx[tid] = (float)(l % WW) + row[tid * 2 + 0];
        sy[tid] = (float)(l / WW) + row[tid * 2 + 1];
    }
    __syncthreads();
    if (tid < 32) {
        const int hh = tid >> 2;
        const float l0 = slog[hh * 4 + 0], l1 = slog[hh * 4 + 1];
        const float l2 = slog[hh * 4 + 2], l3 = slog[hh * 4 + 3];
        const float mx = fmaxf(fmaxf(l0, l1), fmaxf(l2, l3));
        const float e0 = expf(l0 - mx), e1 = expf(l1 - mx);
        const float e2 = expf(l2 - mx), e3 = expf(l3 - mx);
        const float inv = 1.0f / (e0 + e1 + e2 + e3);
        const float ee[4] = {e0, e1, e2, e3};
        sw[tid] = ee[tid & 3] * inv;
    }
    __syncthreads();

    const int c = tid;
    const int hh = c >> 5;
    const ushort* vb = val + (size_t)b * LQ * CDIM;
    float acc = 0.f;
    #pragma unroll
    for (int p = 0; p < POINTS; p++) {
        const float x = sx[hh * 4 + p];
        const float y = sy[hh * 4 + p];
        const float wt = sw[hh * 4 + p];
        const float x0f = floorf(x), y0f = floorf(y);
        const int x0 = (int)x0f, y0 = (int)y0f;
        const float wx = x - x0f, wy = y - y0f;
        float v00 = 0.f, v10 = 0.f, v01 = 0.f, v11 = 0.f;
        const bool xi0 = (x0 >= 0) && (x0 < WW);
        const bool xi1 = (x0 + 1 >= 0) && (x0 + 1 < WW);
        const bool yi0 = (y0 >= 0) && (y0 < HH);
        const bool yi1 = (y0 + 1 >= 0) && (y0 + 1 < HH);
        if (yi0) {
            const ushort* r = vb + (size_t)(y0 * WW) * CDIM;
            if (xi0) v00 = b2f(r[(size_t)x0 * CDIM + c]);
            if (xi1) v10 = b2f(r[(size_t)(x0 + 1) * CDIM + c]);
        }
        if (yi1) {
            const ushort* r = vb + (size_t)((y0 + 1) * WW) * CDIM;
            if (xi0) v01 = b2f(r[(size_t)x0 * CDIM + c]);
            if (xi1) v11 = b2f(r[(size_t)(x0 + 1) * CDIM + c]);
        }
        const float bil = v00 * (1.f - wx) * (1.f - wy) + v10 * wx * (1.f - wy)
                        + v01 * (1.f - wx) * wy + v11 * wx * wy;
        acc = fmaf(wt, bil, acc);
    }
    attn[m * CDIM + c] = f2b(acc);
}

// ---------------------------------------------------------------------------
// Fused residual + LayerNorm. io (fp32) += add; LN -> io (fp32), outb (bf16),
// optionally q = bf16(ln + pos). One wave per 256-wide row, 4 rows/block.
// ---------------------------------------------------------------------------
__global__ __launch_bounds__(256)
void ln_kernel(float* __restrict__ io, const float* __restrict__ add,
               const float* __restrict__ g, const float* __restrict__ beta,
               ushort* __restrict__ outb, ushort* __restrict__ qout,
               const ushort* __restrict__ posb)
{
    const int row = blockIdx.x * 4 + (threadIdx.x >> 6);
    const int lane = threadIdx.x & 63;
    float4* rp = (float4*)(io + (size_t)row * CDIM);
    const float4* ap = (const float4*)(add + (size_t)row * CDIM);
    float4 x = rp[lane];
    const float4 a = ap[lane];
    x.x += a.x; x.y += a.y; x.z += a.z; x.w += a.w;
    float s = x.x + x.y + x.z + x.w;
    float sq = x.x * x.x + x.y * x.y + x.z * x.z + x.w * x.w;
    #pragma unroll
    for (int o = 32; o >= 1; o >>= 1) {
        s += __shfl_xor(s, o, 64);
        sq += __shfl_xor(sq, o, 64);
    }
    const float mean = s * (1.0f / CDIM);
    const float var = sq * (1.0f / CDIM) - mean * mean;
    const float rstd = rsqrtf(var + 1e-5f);
    const float4 gv = *(const float4*)(g + lane * 4);
    const float4 bv = *(const float4*)(beta + lane * 4);
    float4 o4;
    o4.x = (x.x - mean) * rstd * gv.x + bv.x;
    o4.y = (x.y - mean) * rstd * gv.y + bv.y;
    o4.z = (x.z - mean) * rstd * gv.z + bv.z;
    o4.w = (x.w - mean) * rstd * gv.w + bv.w;
    rp[lane] = o4;
    ushort4 ob;
    ob.x = f2b(o4.x); ob.y = f2b(o4.y); ob.z = f2b(o4.z); ob.w = f2b(o4.w);
    *(ushort4*)(outb + (size_t)row * CDIM + lane * 4) = ob;
    if (qout) {
        const int pr = (row >= LQ) ? row - LQ : row;
        const ushort4 pp = *(const ushort4*)(posb + (size_t)pr * CDIM + lane * 4);
        ushort4 qq;
        qq.x = f2b(o4.x + b2f(pp.x)); qq.y = f2b(o4.y + b2f(pp.y));
        qq.z = f2b(o4.z + b2f(pp.z)); qq.w = f2b(o4.w + b2f(pp.w));
        *(ushort4*)(qout + (size_t)row * CDIM + lane * 4) = qq;
    }
}

// ---------------------------------------------------------------------------
// Final transpose: [b, l, c] fp32 -> d_out [b, c, l]
// ---------------------------------------------------------------------------
__global__ __launch_bounds__(256)
void transpose_out(const float* __restrict__ in, float* __restrict__ outp)
{
    __shared__ float tile[32][33];
    const int b = blockIdx.z;
    const int l0 = blockIdx.x * 32;
    const int c0 = blockIdx.y * 32;
    const float* ib = in + (size_t)b * LQ * CDIM;
    float* ob = outp + (size_t)b * CDIM * LQ;
    #pragma unroll
    for (int j = 0; j < 32; j += 8)
        tile[threadIdx.y + j][threadIdx.x] =
            ib[(size_t)(l0 + threadIdx.y + j) * CDIM + c0 + threadIdx.x];
    __syncthreads();
    #pragma unroll
    for (int j = 0; j < 32; j += 8)
        ob[(size_t)(c0 + threadIdx.y + j) * LQ + l0 + threadIdx.x] =
            tile[threadIdx.x][threadIdx.y + j];
}

// ---------------------------------------------------------------------------
extern "C" void kernel_launch(void* const* d_in, const int* in_sizes, int n_in,
                              void* d_out, int out_size, void* d_ws, size_t ws_size,
                              hipStream_t stream)
{
    const float* bev      = (const float*)d_in[0];
    const float* proj_q_w = (const float*)d_in[1];
    const float* proj_q_b = (const float*)d_in[2];
    const float* off_w    = (const float*)d_in[3];
    const float* off_b    = (const float*)d_in[4];
    const float* aw_w     = (const float*)d_in[5];
    const float* aw_b     = (const float*)d_in[6];
    const float* vp_w     = (const float*)d_in[7];
    const float* vp_b     = (const float*)d_in[8];
    const float* op_w     = (const float*)d_in[9];
    const float* op_b     = (const float*)d_in[10];
    const float* ln1_g    = (const float*)d_in[11];
    const float* ln1_b    = (const float*)d_in[12];
    const float* l1_w     = (const float*)d_in[13];
    const float* l1_b     = (const float*)d_in[14];
    const float* l2_w     = (const float*)d_in[15];
    const float* l2_b     = (const float*)d_in[16];
    const float* ln2_g    = (const float*)d_in[17];
    const float* ln2_b    = (const float*)d_in[18];
    float* outp = (float*)d_out;

    // ---- workspace layout (309.1 MB) ----
    char* w = (char*)d_ws;
    float*  out_f = (float*)(w);                       // [MTOT,256] fp32 residual
    float*  tmp_f = (float*)(w + 81920000);            // [MTOT,256] fp32 (attnout/ffn; first half = offaw)
    ushort* out_b = (ushort*)(w + 163840000);          // [MTOT,256] bf16
    ushort* q_b   = (ushort*)(w + 204800000);          // [MTOT,256] bf16 (q / attn alias)
    ushort* val_b = (ushort*)(w + 245760000);          // [MTOT,256] bf16 (bevT / value / hidden)
    ushort* pos_b = (ushort*)(w + 286720000);          // [LQ,256] bf16
    ushort* w_b   = (ushort*)(w + 307200000);          // packed bf16 weights
    ushort* wproj = w_b;                               // 65536
    ushort* wvp   = w_b + 65536;                       // 3*65536
    ushort* wop   = w_b + 65536 + 196608;
    ushort* wl1   = w_b + 65536 + 2 * 196608;
    ushort* wl2   = w_b + 65536 + 3 * 196608;
    ushort* wofa  = w_b + 65536 + 4 * 196608;          // 3*128*256
    float*  bofa  = (float*)(w + 307200000 + 2 * (65536 + 4 * 196608 + 98304)); // 3*128

    const dim3 blk(256);

    // ---- one-time prep (must rerun every call: ws is re-poisoned) ----
    cvt_kernel<<<dim3(65536 / 1024), blk, 0, stream>>>(proj_q_w, wproj);
    cvt_kernel<<<dim3(196608 / 1024), blk, 0, stream>>>(vp_w, wvp);
    cvt_kernel<<<dim3(196608 / 1024), blk, 0, stream>>>(op_w, wop);
    cvt_kernel<<<dim3(196608 / 1024), blk, 0, stream>>>(l1_w, wl1);
    cvt_kernel<<<dim3(196608 / 1024), blk, 0, stream>>>(l2_w, wl2);
    build_offaw<<<dim3(3 * 128), blk, 0, stream>>>(off_w, off_b, aw_w, aw_b, wofa, bofa);
    pos_kernel<<<dim3((LQ * CDIM) / 256), blk, 0, stream>>>(pos_b);
    bevT_kernel<<<dim3(LQ / 32, CDIM / 32, BSZ), dim3(32, 8), 0, stream>>>(bev, val_b);

    const dim3 g256(CDIM / 128, MTOT / 128);   // (2, 625)
    const dim3 g128(1, MTOT / 128);            // (1, 625)

    // proj: out = bevT @ Wq^T + b ; also bf16 copy + q = bf16(out+pos)
    mfma_gemm<false, true, true, true><<<g256, blk, 0, stream>>>(
        val_b, wproj, proj_q_b, out_f, out_b, q_b, pos_b, CDIM, CDIM);

    for (int i = 0; i < NLAYERS; i++) {
        // value = out @ vp^T  (bf16)
        mfma_gemm<false, false, true, false><<<g256, blk, 0, stream>>>(
            out_b, wvp + (size_t)i * 65536, vp_b + (size_t)i * CDIM,
            nullptr, val_b, nullptr, nullptr, CDIM, CDIM);
        // offaw = q @ [off;aw]^T  (fp32, N=128, into tmp_f front half)
        mfma_gemm<false, true, false, false><<<g128, blk, 0, stream>>>(
            q_b, wofa + (size_t)i * 32768, bofa + (size_t)i * 128,
            tmp_f, nullptr, nullptr, nullptr, 128, CDIM);
        // sampling -> attn (bf16, into q_b; q is dead now)
        sample_kernel<<<dim3(LQ, BSZ), blk, 0, stream>>>(val_b, tmp_f, q_b);
        // attn_out = attn @ op^T (fp32)
        mfma_gemm<false, true, false, false><<<g256, blk, 0, stream>>>(
            q_b, wop + (size_t)i * 65536, op_b + (size_t)i * CDIM,
            tmp_f, nullptr, nullptr, nullptr, CDIM, CDIM);
        // out = LN(out + attn_out); bf16 copy
        ln_kernel<<<dim3(MTOT / 4), blk, 0, stream>>>(
            out_f, tmp_f, ln1_g + (size_t)i * CDIM, ln1_b + (size_t)i * CDIM,
            out_b, nullptr, pos_b);
        // hidden = relu(out @ l1^T) (bf16)
        mfma_gemm<true, false, true, false><<<g256, blk, 0, stream>>>(
            out_b, wl1 + (size_t)i * 65536, l1_b + (size_t)i * CDIM,
            nullptr, val_b, nullptr, nullptr, CDIM, CDIM);
        // ffn = hidden @ l2^T (fp32)
        mfma_gemm<false, true, false, false><<<g256, blk, 0, stream>>>(
            val_b, wl2 + (size_t)i * 65536, l2_b + (size_t)i * CDIM,
            tmp_f, nullptr, nullptr, nullptr, CDIM, CDIM);
        // out = LN(out + ffn); bf16 copy + q for next layer
        ln_kernel<<<dim3(MTOT / 4), blk, 0, stream>>>(
            out_f, tmp_f, ln2_g + (size_t)i * CDIM, ln2_b + (size_t)i * CDIM,
            out_b, q_b, pos_b);
    }

    transpose_out<<<dim3(LQ / 32, CDIM / 32, BSZ), dim3(32, 8), 0, stream>>>(out_f, outp);
}

// Round 5
// 1136.097 us; speedup vs baseline: 2.5427x; 1.4919x over previous
//
#include <hip/hip_runtime.h>
#include <math.h>

#define HEADS 8
#define POINTS 4
#define BSZ 2
#define CDIM 256
#define HH 200
#define WW 200
#define LQ (HH * WW)          // 40000
#define MTOT (BSZ * LQ)       // 80000 rows, batch folded into M
#define NLAYERS 3

typedef __attribute__((ext_vector_type(8))) short shortx8;   // 8 bf16 = 4 VGPR
typedef __attribute__((ext_vector_type(4))) float floatx4;

__device__ __forceinline__ ushort f2b(float f) {
    union { float f; unsigned u; } v; v.f = f;
    unsigned r = v.u + 0x7fffu + ((v.u >> 16) & 1u);   // RNE
    return (ushort)(r >> 16);
}
__device__ __forceinline__ float b2f(ushort b) {
    union { unsigned u; float f; } v; v.u = ((unsigned)b) << 16;
    return v.f;
}
__device__ __forceinline__ float bitsf(unsigned u) {
    union { unsigned u; float f; } v; v.u = u;
    return v.f;
}

// ---------------------------------------------------------------------------
// fp32 -> bf16 convert (n multiple of 1024)
// ---------------------------------------------------------------------------
__global__ __launch_bounds__(256)
void cvt_kernel(const float* __restrict__ in, ushort* __restrict__ out)
{
    const int i = (blockIdx.x * 256 + threadIdx.x) * 4;
    const float4 v = *(const float4*)(in + i);
    ushort4 o;
    o.x = f2b(v.x); o.y = f2b(v.y); o.z = f2b(v.z); o.w = f2b(v.w);
    *(ushort4*)(out + i) = o;
}

// ---------------------------------------------------------------------------
// Build packed off+aw weight [3][128][256] bf16 (rows 0..63 off, 64..95 aw,
// 96..127 zero) and bias [3][128] fp32.
// ---------------------------------------------------------------------------
__global__ __launch_bounds__(256)
void build_offaw(const float* __restrict__ offw, const float* __restrict__ offb,
                 const float* __restrict__ aww, const float* __restrict__ awb,
                 ushort* __restrict__ wout, float* __restrict__ bout)
{
    const int blk = blockIdx.x;          // 3*128 blocks
    const int i = blk >> 7;
    const int r = blk & 127;
    const int c = threadIdx.x;
    float v = 0.f;
    if (r < 64)      v = offw[((size_t)i * 64 + r) * CDIM + c];
    else if (r < 96) v = aww[((size_t)i * 32 + (r - 64)) * CDIM + c];
    wout[((size_t)i * 128 + r) * CDIM + c] = f2b(v);
    if (c == 0) {
        float bb = 0.f;
        if (r < 64)      bb = offb[i * 64 + r];
        else if (r < 96) bb = awb[i * 32 + (r - 64)];
        bout[i * 128 + r] = bb;
    }
}

// ---------------------------------------------------------------------------
// Sine positional encoding -> bf16 [LQ, 256]
// ---------------------------------------------------------------------------
__global__ __launch_bounds__(256)
void pos_kernel(ushort* __restrict__ pos)
{
    const int idx = blockIdx.x * 256 + threadIdx.x;
    const int c = idx & 255;
    const int l = idx >> 8;
    const int cc = c & 127;
    const float coord = (c < 128) ? (float)(l / WW + 1) : (float)(l % WW + 1);
    const float expo = (float)(2 * (cc >> 1)) * (1.0f / 128.0f);
    const float t = powf(10000.0f, expo);
    const float ph = coord / t;
    pos[idx] = f2b((cc & 1) ? cosf(ph) : sinf(ph));
}

// ---------------------------------------------------------------------------
// bev [BS, C, HW] fp32 -> [BS*HW, C] bf16 (32x32 LDS transpose tiles)
// ---------------------------------------------------------------------------
__global__ __launch_bounds__(256)
void bevT_kernel(const float* __restrict__ in, ushort* __restrict__ out)
{
    __shared__ float tile[32][33];
    const int b = blockIdx.z;
    const int l0 = blockIdx.x * 32;
    const int c0 = blockIdx.y * 32;
    const float* ib = in + (size_t)b * CDIM * LQ;
    ushort* ob = out + (size_t)b * LQ * CDIM;
    #pragma unroll
    for (int j = 0; j < 32; j += 8)
        tile[threadIdx.y + j][threadIdx.x] =
            ib[(size_t)(c0 + threadIdx.y + j) * LQ + l0 + threadIdx.x];
    __syncthreads();
    #pragma unroll
    for (int j = 0; j < 32; j += 8)
        ob[(size_t)(l0 + threadIdx.y + j) * CDIM + c0 + threadIdx.x] =
            f2b(tile[threadIdx.x][threadIdx.y + j]);
}

// ---------------------------------------------------------------------------
// MFMA bf16 GEMM: C[m,n] = sum_k A[m,k]*B[n,k] + bias[n]
// A [M,K] bf16, B [N,K] bf16, fp32 accumulate. 128x128 tile, BK=32,
// 256 thr = 4 waves (2x2 of 64x64), 16x16x32 MFMA, 4x4 tiles/wave.
// ---------------------------------------------------------------------------
#define LSTR 40   // LDS row stride in shorts (80 B = 5*16, breaks 2^k banks)

template<bool RELU, bool F32OUT, bool BF16OUT, bool QOUT>
__global__ __launch_bounds__(256)
void mfma_gemm(const ushort* __restrict__ A, const ushort* __restrict__ B,
               const float* __restrict__ bias,
               float* __restrict__ Cf, ushort* __restrict__ Cb,
               ushort* __restrict__ Cq, const ushort* __restrict__ posb,
               int N, int K)
{
    __shared__ ushort As[128 * LSTR];
    __shared__ ushort Bs[128 * LSTR];
    const int tid = threadIdx.x;
    const int lane = tid & 63;
    const int wave = tid >> 6;
    const int wr = (wave >> 1) * 64;
    const int wc = (wave & 1) * 64;
    const int rowBase = blockIdx.y * 128;
    const int colBase = blockIdx.x * 128;

    floatx4 acc[4][4];
    #pragma unroll
    for (int i = 0; i < 4; i++)
        #pragma unroll
        for (int j = 0; j < 4; j++) {
            floatx4 z = {0.f, 0.f, 0.f, 0.f};
            acc[i][j] = z;
        }

    const int strow = tid >> 2;          // 0..63
    const int stcol = (tid & 3) * 8;     // 0,8,16,24
    const int kq = (lane >> 4) * 8;      // fragment k offset
    const int lr = lane & 15;

    for (int k0 = 0; k0 < K; k0 += 32) {
        #pragma unroll
        for (int j = 0; j < 2; j++) {
            const int r = j * 64 + strow;
            const uint4 av = *(const uint4*)(A + (size_t)(rowBase + r) * K + k0 + stcol);
            const uint4 bv = *(const uint4*)(B + (size_t)(colBase + r) * K + k0 + stcol);
            *(uint4*)(As + r * LSTR + stcol) = av;
            *(uint4*)(Bs + r * LSTR + stcol) = bv;
        }
        __syncthreads();
        shortx8 af[4], bf[4];
        #pragma unroll
        for (int t = 0; t < 4; t++) {
            af[t] = *(const shortx8*)(As + (wr + t * 16 + lr) * LSTR + kq);
            bf[t] = *(const shortx8*)(Bs + (wc + t * 16 + lr) * LSTR + kq);
        }
        #pragma unroll
        for (int mt = 0; mt < 4; mt++)
            #pragma unroll
            for (int nt = 0; nt < 4; nt++)
                acc[mt][nt] = __builtin_amdgcn_mfma_f32_16x16x32_bf16(
                    af[mt], bf[nt], acc[mt][nt], 0, 0, 0);
        __syncthreads();
    }

    // epilogue: C/D layout col=lane&15, row=(lane>>4)*4+reg  [m89/m91 verified]
    const int colB = colBase + wc + lr;
    const int rowB = rowBase + wr + (lane >> 4) * 4;
    #pragma unroll
    for (int mt = 0; mt < 4; mt++) {
        #pragma unroll
        for (int r = 0; r < 4; r++) {
            const int m = rowB + mt * 16 + r;
            const int pr = (m >= LQ) ? m - LQ : m;   // pos row (batch-folded)
            #pragma unroll
            for (int nt = 0; nt < 4; nt++) {
                const int n = colB + nt * 16;
                float v = acc[mt][nt][r] + bias[n];
                if (RELU) v = fmaxf(v, 0.f);
                if (F32OUT) Cf[(size_t)m * N + n] = v;
                if (BF16OUT) Cb[(size_t)m * N + n] = f2b(v);
                if (QOUT) {
                    const float pv = b2f(posb[(size_t)pr * CDIM + n]);
                    Cq[(size_t)m * N + n] = f2b(v + pv);
                }
            }
        }
    }
}

// ---------------------------------------------------------------------------
// Deformable sampling, wave-per-query. 256 thr = 4 waves = 4 queries/block.
// lane: head = lane>>3, channel quad = (lane&7)*4 -> each lane produces 4
// output channels via uint2 (4 x bf16) gathers. No LDS, no barriers; validity
// and attention weight folded into per-corner scalar weights so all 16 loads
// are unconditional and batched.
// val bf16 [BSZ,LQ,256]; offaw fp32 [MTOT,128] (0..63 offsets, 64..95 logits)
// ---------------------------------------------------------------------------
__global__ __launch_bounds__(256)
void sample_kernel(const ushort* __restrict__ val,
                   const float* __restrict__ offaw,
                   ushort* __restrict__ attn)
{
    const int wave = threadIdx.x >> 6;
    const int lane = threadIdx.x & 63;
    const int m = blockIdx.x * 4 + wave;         // grid.x = MTOT/4
    const int b = (m >= LQ) ? 1 : 0;
    const int l = m - b * LQ;
    const int head = lane >> 3;
    const int c = head * 32 + (lane & 7) * 4;

    const float* row = offaw + (size_t)m * 128;
    const float4 lg  = *(const float4*)(row + 64 + head * 4);
    const float4 o01 = *(const float4*)(row + head * 8);
    const float4 o23 = *(const float4*)(row + head * 8 + 4);

    const float mx = fmaxf(fmaxf(lg.x, lg.y), fmaxf(lg.z, lg.w));
    const float e0 = expf(lg.x - mx), e1 = expf(lg.y - mx);
    const float e2 = expf(lg.z - mx), e3 = expf(lg.w - mx);
    const float inv = 1.0f / (e0 + e1 + e2 + e3);
    const float awv[4] = {e0 * inv, e1 * inv, e2 * inv, e3 * inv};

    const float lx = (float)(l % WW);
    const float ly = (float)(l / WW);
    const float px[4] = {lx + o01.x, lx + o01.z, lx + o23.x, lx + o23.z};
    const float py[4] = {ly + o01.y, ly + o01.w, ly + o23.y, ly + o23.w};

    const ushort* vb = val + (size_t)b * LQ * CDIM;
    uint2 cv[16];
    float cw[16];
    #pragma unroll
    for (int p = 0; p < POINTS; p++) {
        const float x = px[p], y = py[p];
        const float xf = floorf(x), yf = floorf(y);
        const int x0 = (int)xf, y0 = (int)yf;
        const float wx = x - xf, wy = y - yf;
        const int x0c = min(max(x0, 0), WW - 1);
        const int x1c = min(max(x0 + 1, 0), WW - 1);
        const int y0c = min(max(y0, 0), HH - 1);
        const int y1c = min(max(y0 + 1, 0), HH - 1);
        const float vx0 = (x0 >= 0 && x0 < WW) ? 1.f : 0.f;
        const float vx1 = (x0 + 1 >= 0 && x0 + 1 < WW) ? 1.f : 0.f;
        const float vy0 = (y0 >= 0 && y0 < HH) ? 1.f : 0.f;
        const float vy1 = (y0 + 1 >= 0 && y0 + 1 < HH) ? 1.f : 0.f;
        const float a = awv[p];
        cw[p * 4 + 0] = a * (1.f - wx) * (1.f - wy) * vx0 * vy0;
        cw[p * 4 + 1] = a * wx * (1.f - wy) * vx1 * vy0;
        cw[p * 4 + 2] = a * (1.f - wx) * wy * vx0 * vy1;
        cw[p * 4 + 3] = a * wx * wy * vx1 * vy1;
        const int r0 = y0c * WW, r1 = y1c * WW;
        cv[p * 4 + 0] = *(const uint2*)(vb + (size_t)(r0 + x0c) * CDIM + c);
        cv[p * 4 + 1] = *(const uint2*)(vb + (size_t)(r0 + x1c) * CDIM + c);
        cv[p * 4 + 2] = *(const uint2*)(vb + (size_t)(r1 + x0c) * CDIM + c);
        cv[p * 4 + 3] = *(const uint2*)(vb + (size_t)(r1 + x1c) * CDIM + c);
    }
    float a0 = 0.f, a1 = 0.f, a2 = 0.f, a3 = 0.f;
    #pragma unroll
    for (int i = 0; i < 16; i++) {
        const float wgt = cw[i];
        a0 = fmaf(wgt, bitsf(cv[i].x << 16), a0);
        a1 = fmaf(wgt, bitsf(cv[i].x & 0xffff0000u), a1);
        a2 = fmaf(wgt, bitsf(cv[i].y << 16), a2);
        a3 = fmaf(wgt, bitsf(cv[i].y & 0xffff0000u), a3);
    }
    ushort4 o;
    o.x = f2b(a0); o.y = f2b(a1); o.z = f2b(a2); o.w = f2b(a3);
    *(ushort4*)(attn + (size_t)m * CDIM + c) = o;
}

// ---------------------------------------------------------------------------
// Fused residual + LayerNorm. io (fp32) += add (bf16); LN -> io (fp32),
// outb (bf16), optionally q = bf16(ln + pos). One wave per row, 4 rows/block.
// ---------------------------------------------------------------------------
__global__ __launch_bounds__(256)
void ln_kernel(float* __restrict__ io, const ushort* __restrict__ add,
               const float* __restrict__ g, const float* __restrict__ beta,
               ushort* __restrict__ outb, ushort* __restrict__ qout,
               const ushort* __restrict__ posb)
{
    const int row = blockIdx.x * 4 + (threadIdx.x >> 6);
    const int lane = threadIdx.x & 63;
    float4* rp = (float4*)(io + (size_t)row * CDIM);
    float4 x = rp[lane];
    const ushort4 av = *(const ushort4*)(add + (size_t)row * CDIM + lane * 4);
    x.x += b2f(av.x); x.y += b2f(av.y); x.z += b2f(av.z); x.w += b2f(av.w);
    float s = x.x + x.y + x.z + x.w;
    float sq = x.x * x.x + x.y * x.y + x.z * x.z + x.w * x.w;
    #pragma unroll
    for (int o = 32; o >= 1; o >>= 1) {
        s += __shfl_xor(s, o, 64);
        sq += __shfl_xor(sq, o, 64);
    }
    const float mean = s * (1.0f / CDIM);
    const float var = sq * (1.0f / CDIM) - mean * mean;
    const float rstd = rsqrtf(var + 1e-5f);
    const float4 gv = *(const float4*)(g + lane * 4);
    const float4 bv = *(const float4*)(beta + lane * 4);
    float4 o4;
    o4.x = (x.x - mean) * rstd * gv.x + bv.x;
    o4.y = (x.y - mean) * rstd * gv.y + bv.y;
    o4.z = (x.z - mean) * rstd * gv.z + bv.z;
    o4.w = (x.w - mean) * rstd * gv.w + bv.w;
    rp[lane] = o4;
    ushort4 ob;
    ob.x = f2b(o4.x); ob.y = f2b(o4.y); ob.z = f2b(o4.z); ob.w = f2b(o4.w);
    *(ushort4*)(outb + (size_t)row * CDIM + lane * 4) = ob;
    if (qout) {
        const int pr = (row >= LQ) ? row - LQ : row;
        const ushort4 pp = *(const ushort4*)(posb + (size_t)pr * CDIM + lane * 4);
        ushort4 qq;
        qq.x = f2b(o4.x + b2f(pp.x)); qq.y = f2b(o4.y + b2f(pp.y));
        qq.z = f2b(o4.z + b2f(pp.z)); qq.w = f2b(o4.w + b2f(pp.w));
        *(ushort4*)(qout + (size_t)row * CDIM + lane * 4) = qq;
    }
}

// ---------------------------------------------------------------------------
// Final transpose: [b, l, c] fp32 -> d_out [b, c, l]
// ---------------------------------------------------------------------------
__global__ __launch_bounds__(256)
void transpose_out(const float* __restrict__ in, float* __restrict__ outp)
{
    __shared__ float tile[32][33];
    const int b = blockIdx.z;
    const int l0 = blockIdx.x * 32;
    const int c0 = blockIdx.y * 32;
    const float* ib = in + (size_t)b * LQ * CDIM;
    float* ob = outp + (size_t)b * CDIM * LQ;
    #pragma unroll
    for (int j = 0; j < 32; j += 8)
        tile[threadIdx.y + j][threadIdx.x] =
            ib[(size_t)(l0 + threadIdx.y + j) * CDIM + c0 + threadIdx.x];
    __syncthreads();
    #pragma unroll
    for (int j = 0; j < 32; j += 8)
        ob[(size_t)(c0 + threadIdx.y + j) * LQ + l0 + threadIdx.x] =
            tile[threadIdx.x][threadIdx.y + j];
}

// ---------------------------------------------------------------------------
extern "C" void kernel_launch(void* const* d_in, const int* in_sizes, int n_in,
                              void* d_out, int out_size, void* d_ws, size_t ws_size,
                              hipStream_t stream)
{
    const float* bev      = (const float*)d_in[0];
    const float* proj_q_w = (const float*)d_in[1];
    const float* proj_q_b = (const float*)d_in[2];
    const float* off_w    = (const float*)d_in[3];
    const float* off_b    = (const float*)d_in[4];
    const float* aw_w     = (const float*)d_in[5];
    const float* aw_b     = (const float*)d_in[6];
    const float* vp_w     = (const float*)d_in[7];
    const float* vp_b     = (const float*)d_in[8];
    const float* op_w     = (const float*)d_in[9];
    const float* op_b     = (const float*)d_in[10];
    const float* ln1_g    = (const float*)d_in[11];
    const float* ln1_b    = (const float*)d_in[12];
    const float* l1_w     = (const float*)d_in[13];
    const float* l1_b     = (const float*)d_in[14];
    const float* l2_w     = (const float*)d_in[15];
    const float* l2_b     = (const float*)d_in[16];
    const float* ln2_g    = (const float*)d_in[17];
    const float* ln2_b    = (const float*)d_in[18];
    float* outp = (float*)d_out;

    // ---- workspace layout ----
    char* w = (char*)d_ws;
    float*  out_f   = (float*)(w);                     // [MTOT,256] fp32 residual
    float*  offaw_f = (float*)(w + 81920000);          // [MTOT,128] fp32
    ushort* tmp_b   = (ushort*)(w + 122880000);        // [MTOT,256] bf16 (attnout/ffn)
    ushort* out_b   = (ushort*)(w + 163840000);        // [MTOT,256] bf16
    ushort* q_b     = (ushort*)(w + 204800000);        // [MTOT,256] bf16 (q / attn alias)
    ushort* val_b   = (ushort*)(w + 245760000);        // [MTOT,256] bf16 (bevT / value / hidden)
    ushort* pos_b   = (ushort*)(w + 286720000);        // [LQ,256] bf16
    ushort* w_b     = (ushort*)(w + 307200000);        // packed bf16 weights
    ushort* wproj = w_b;                               // 65536
    ushort* wvp   = w_b + 65536;                       // 3*65536
    ushort* wop   = w_b + 65536 + 196608;
    ushort* wl1   = w_b + 65536 + 2 * 196608;
    ushort* wl2   = w_b + 65536 + 3 * 196608;
    ushort* wofa  = w_b + 65536 + 4 * 196608;          // 3*128*256
    float*  bofa  = (float*)(w + 307200000 + 2 * (65536 + 4 * 196608 + 98304)); // 3*128

    const dim3 blk(256);

    // ---- one-time prep (rerun every call: ws is re-poisoned) ----
    cvt_kernel<<<dim3(65536 / 1024), blk, 0, stream>>>(proj_q_w, wproj);
    cvt_kernel<<<dim3(196608 / 1024), blk, 0, stream>>>(vp_w, wvp);
    cvt_kernel<<<dim3(196608 / 1024), blk, 0, stream>>>(op_w, wop);
    cvt_kernel<<<dim3(196608 / 1024), blk, 0, stream>>>(l1_w, wl1);
    cvt_kernel<<<dim3(196608 / 1024), blk, 0, stream>>>(l2_w, wl2);
    build_offaw<<<dim3(3 * 128), blk, 0, stream>>>(off_w, off_b, aw_w, aw_b, wofa, bofa);
    pos_kernel<<<dim3((LQ * CDIM) / 256), blk, 0, stream>>>(pos_b);
    bevT_kernel<<<dim3(LQ / 32, CDIM / 32, BSZ), dim3(32, 8), 0, stream>>>(bev, val_b);

    const dim3 g256(CDIM / 128, MTOT / 128);   // (2, 625)
    const dim3 g128(1, MTOT / 128);            // (1, 625)

    // proj: out = bevT @ Wq^T + b ; fp32 + bf16 + q = bf16(out+pos)
    mfma_gemm<false, true, true, true><<<g256, blk, 0, stream>>>(
        val_b, wproj, proj_q_b, out_f, out_b, q_b, pos_b, CDIM, CDIM);

    for (int i = 0; i < NLAYERS; i++) {
        // value = out @ vp^T  (bf16)
        mfma_gemm<false, false, true, false><<<g256, blk, 0, stream>>>(
            out_b, wvp + (size_t)i * 65536, vp_b + (size_t)i * CDIM,
            nullptr, val_b, nullptr, nullptr, CDIM, CDIM);
        // offaw = q @ [off;aw]^T  (fp32, N=128)
        mfma_gemm<false, true, false, false><<<g128, blk, 0, stream>>>(
            q_b, wofa + (size_t)i * 32768, bofa + (size_t)i * 128,
            offaw_f, nullptr, nullptr, nullptr, 128, CDIM);
        // sampling -> attn (bf16, into q_b; q is dead now)
        sample_kernel<<<dim3(MTOT / 4), blk, 0, stream>>>(val_b, offaw_f, q_b);
        // attn_out = attn @ op^T (bf16)
        mfma_gemm<false, false, true, false><<<g256, blk, 0, stream>>>(
            q_b, wop + (size_t)i * 65536, op_b + (size_t)i * CDIM,
            nullptr, tmp_b, nullptr, nullptr, CDIM, CDIM);
        // out = LN(out + attn_out); bf16 copy
        ln_kernel<<<dim3(MTOT / 4), blk, 0, stream>>>(
            out_f, tmp_b, ln1_g + (size_t)i * CDIM, ln1_b + (size_t)i * CDIM,
            out_b, nullptr, pos_b);
        // hidden = relu(out @ l1^T) (bf16)
        mfma_gemm<true, false, true, false><<<g256, blk, 0, stream>>>(
            out_b, wl1 + (size_t)i * 65536, l1_b + (size_t)i * CDIM,
            nullptr, val_b, nullptr, nullptr, CDIM, CDIM);
        // ffn = hidden @ l2^T (bf16)
        mfma_gemm<false, false, true, false><<<g256, blk, 0, stream>>>(
            val_b, wl2 + (size_t)i * 65536, l2_b + (size_t)i * CDIM,
            nullptr, tmp_b, nullptr, nullptr, CDIM, CDIM);
        // out = LN(out + ffn); bf16 copy + q for next layer
        ln_kernel<<<dim3(MTOT / 4), blk, 0, stream>>>(
            out_f, tmp_b, ln2_g + (size_t)i * CDIM, ln2_b + (size_t)i * CDIM,
            out_b, q_b, pos_b);
    }

    transpose_out<<<dim3(LQ / 32, CDIM / 32, BSZ), dim3(32, 8), 0, stream>>>(out_f, outp);
}